// Round 2
// baseline (128.666 us; speedup 1.0000x reference)
//
#include <hip/hip_runtime.h>

#define DEVI __device__ __forceinline__

typedef int i32x4 __attribute__((ext_vector_type(4)));

static constexpr int Bdim = 2048;
static constexpr int Kdim = 4096;
static constexpr int Ndim = 8192;
static constexpr int BK   = 64;          // int8 k-elements per tile
static constexpr int NT   = Kdim / BK;   // 64 K-iterations

typedef __attribute__((address_space(1))) const unsigned int gas_t;
typedef __attribute__((address_space(3))) unsigned int las_t;

DEVI void gload_lds16(const void* g, void* l) {
    __builtin_amdgcn_global_load_lds((gas_t*)g, (las_t*)l, 16, 0, 0);
}

DEVI int pack4(i32x4 v) {
    return (v[0] & 255) | ((v[1] & 255) << 8) | ((v[2] & 255) << 16) | (v[3] << 24);
}

// ---------------- pack: int32 -> int8 ----------------
__global__ void pack_i32_to_i8(const int* __restrict__ in, char* __restrict__ out, int n16) {
    int i = blockIdx.x * blockDim.x + threadIdx.x;
    if (i >= n16) return;
    const i32x4* src = (const i32x4*)in + (size_t)i * 4;
    i32x4 r;
    r[0] = pack4(src[0]);
    r[1] = pack4(src[1]);
    r[2] = pack4(src[2]);
    r[3] = pack4(src[3]);
    ((i32x4*)out)[i] = r;
}

// ---------------- GEMM ----------------
// PACKED=true : Ap/Bp are int8 (packed in ws), staged via global_load_lds
// PACKED=false: Ap/Bp are int32 (raw inputs), reg-staged + packed + ds_write
template <bool PACKED>
__global__ __launch_bounds__(256, 2)
void gemm_i8(const void* __restrict__ Ap, const void* __restrict__ Bp,
             const int* __restrict__ bias,
             const int* __restrict__ qm_p, const int* __restrict__ ex_p,
             const int* __restrict__ zp_p, int* __restrict__ out) {
    __shared__ __align__(16) char lds[2][2][128 * BK];  // [buf][A/B][8KB]

    const int tid  = threadIdx.x;
    const int wid  = tid >> 6;
    const int lane = tid & 63;
    const int wr   = wid >> 1;        // 0..1
    const int wc   = wid & 1;         // 0..1
    const int l15  = lane & 15;
    const int lks  = lane >> 4;       // 0..3

    // XCD-aware bijective swizzle (nwg = 1024, divisible by 8)
    const int nwg = gridDim.x;
    const int bid = blockIdx.x;
    const int swz = (bid & 7) * (nwg >> 3) + (bid >> 3);
    const int bm  = swz >> 6;   // 0..15
    const int bn  = swz & 63;   // 0..63
    const size_t arow = (size_t)bm * 128;
    const size_t brow = (size_t)bn * 128;

    i32x4 acc[4][4] = {};

    auto stage = [&](int buf, int t) {
        const int k0 = t * BK;
        if constexpr (PACKED) {
            const char* A8 = (const char*)Ap;
            const char* B8 = (const char*)Bp;
#pragma unroll
            for (int j = 0; j < 2; ++j) {
                const int idx = tid + j * 256;      // 0..511 (16B slots)
                const int r   = idx >> 2;           // row 0..127
                const int s   = (idx & 3) * 16;     // 16B slot within row
                gload_lds16(A8 + (arow + r) * (size_t)Kdim + k0 + s,
                            &lds[buf][0][idx * 16]);
                gload_lds16(B8 + (brow + r) * (size_t)Kdim + k0 + s,
                            &lds[buf][1][idx * 16]);
            }
        } else {
            const int* A32 = (const int*)Ap;
            const int* B32 = (const int*)Bp;
            const int r  = tid >> 1;            // row 0..127
            const int kk = (tid & 1) * 32;      // k-offset 0/32
            const int* sa = A32 + (arow + r) * (size_t)Kdim + k0 + kk;
            const int* sb = B32 + (brow + r) * (size_t)Kdim + k0 + kk;
            const int dst = r * BK + kk;
#pragma unroll
            for (int g = 0; g < 2; ++g) {
                i32x4 pa, pb;
#pragma unroll
                for (int q = 0; q < 4; ++q) {
                    i32x4 va = *(const i32x4*)(sa + g * 16 + q * 4);
                    i32x4 vb = *(const i32x4*)(sb + g * 16 + q * 4);
                    pa[q] = pack4(va);
                    pb[q] = pack4(vb);
                }
                *(i32x4*)&lds[buf][0][dst + g * 16] = pa;
                *(i32x4*)&lds[buf][1][dst + g * 16] = pb;
            }
        }
    };

    auto compute = [&](int buf) {
        i32x4 a[4], b[4];
#pragma unroll
        for (int m = 0; m < 4; ++m) {
            const int row = wr * 64 + m * 16 + l15;
            a[m] = *(const i32x4*)&lds[buf][0][row * BK + lks * 16];
        }
#pragma unroll
        for (int n = 0; n < 4; ++n) {
            const int row = wc * 64 + n * 16 + l15;
            b[n] = *(const i32x4*)&lds[buf][1][row * BK + lks * 16];
        }
#pragma unroll
        for (int m = 0; m < 4; ++m)
#pragma unroll
            for (int n = 0; n < 4; ++n)
                acc[m][n] = __builtin_amdgcn_mfma_i32_16x16x64_i8(a[m], b[n], acc[m][n], 0, 0, 0);
    };

    stage(0, 0);
    __syncthreads();
    int cur = 0;
    for (int t = 0; t < NT - 1; ++t) {
        stage(cur ^ 1, t + 1);
        compute(cur);
        __syncthreads();
        cur ^= 1;
    }
    compute(cur);

    // ---------------- epilogue: requantize ----------------
    const int qm = *qm_p;
    const int ex = *ex_p;
    const int zp = *zp_p;
    const int rm = (qm < 2147418112) ? ((qm + (1 << 15)) >> 16) : 32767;
    const int shifts = 15 - ex;
    const long long rnd = (shifts > 0) ? (1LL << (shifts - 1)) : 0;

#pragma unroll
    for (int n = 0; n < 4; ++n) {
        const int col = bn * 128 + wc * 64 + n * 16 + l15;
        const int bv  = bias[col];
#pragma unroll
        for (int m = 0; m < 4; ++m) {
            const int row0 = bm * 128 + wr * 64 + m * 16 + (lane >> 4) * 4;
#pragma unroll
            for (int j = 0; j < 4; ++j) {
                long long t = (long long)(acc[m][n][j] + bv) * rm + rnd;
                t >>= shifts;
                t += zp;
                t = t < -128 ? -128 : (t > 127 ? 127 : t);
                out[(size_t)(row0 + j) * Ndim + col] = (int)t;
            }
        }
    }
}

extern "C" void kernel_launch(void* const* d_in, const int* in_sizes, int n_in,
                              void* d_out, int out_size, void* d_ws, size_t ws_size,
                              hipStream_t stream) {
    const int* x32  = (const int*)d_in[0];
    const int* w32  = (const int*)d_in[1];
    const int* bias = (const int*)d_in[2];
    const int* qm   = (const int*)d_in[3];
    const int* ex   = (const int*)d_in[4];
    const int* zp   = (const int*)d_in[5];
    int* out = (int*)d_out;

    const size_t need = (size_t)Bdim * Kdim + (size_t)Ndim * Kdim;  // ~42 MB
    const int grid = (Bdim / 128) * (Ndim / 128);                   // 1024

    if (ws_size >= need) {
        char* xa = (char*)d_ws;
        char* wa = xa + (size_t)Bdim * Kdim;
        const int nx16 = Bdim * Kdim / 16;   // 524288
        const int nw16 = Ndim * Kdim / 16;   // 2097152
        pack_i32_to_i8<<<(nx16 + 255) / 256, 256, 0, stream>>>(x32, xa, nx16);
        pack_i32_to_i8<<<(nw16 + 255) / 256, 256, 0, stream>>>(w32, wa, nw16);
        gemm_i8<true><<<grid, 256, 0, stream>>>(xa, wa, bias, qm, ex, zp, out);
    } else {
        gemm_i8<false><<<grid, 256, 0, stream>>>(x32, w32, bias, qm, ex, zp, out);
    }
}

// Round 3
// 107.810 us; speedup vs baseline: 1.1935x; 1.1935x over previous
//
#include <hip/hip_runtime.h>

#define DEVI __device__ __forceinline__

typedef int i32x4 __attribute__((ext_vector_type(4)));

static constexpr int Bdim = 2048;
static constexpr int Kdim = 4096;
static constexpr int Ndim = 8192;
static constexpr int BK   = 128;         // int8 k-elements per tile (128 B/row)
static constexpr int NT   = Kdim / BK;   // 32 K-tiles

typedef __attribute__((address_space(1))) const unsigned int gas_t;
typedef __attribute__((address_space(3))) unsigned int las_t;

DEVI void gload_lds16(const void* g, void* l) {
    __builtin_amdgcn_global_load_lds((gas_t*)g, (las_t*)l, 16, 0, 0);
}

DEVI int pack4(i32x4 v) {
    return (v[0] & 255) | ((v[1] & 255) << 8) | ((v[2] & 255) << 16) | (v[3] << 24);
}

// ---------------- pack: int32 -> int8 ----------------
__global__ void pack_i32_to_i8(const int* __restrict__ in, char* __restrict__ out, int n16) {
    int i = blockIdx.x * blockDim.x + threadIdx.x;
    if (i >= n16) return;
    const i32x4* src = (const i32x4*)in + (size_t)i * 4;
    i32x4 r;
    r[0] = pack4(src[0]);
    r[1] = pack4(src[1]);
    r[2] = pack4(src[2]);
    r[3] = pack4(src[3]);
    ((i32x4*)out)[i] = r;
}

// ---------------- 256x256 8-phase i8 GEMM ----------------
#define CFENCE asm volatile("" ::: "memory")
DEVI void bar() { CFENCE; __builtin_amdgcn_s_barrier(); CFENCE; }
#define WAITVM(N) asm volatile("s_waitcnt vmcnt(" #N ")" ::: "memory")
#define PRIO1 __builtin_amdgcn_s_setprio(1)
#define PRIO0 __builtin_amdgcn_s_setprio(0)

// acc[MB..MB+3][0..3] += a[0..3] x b[0..3], compile-time MB (rule #20)
#define QUAD(MB)                                                                 \
    do {                                                                         \
        _Pragma("unroll") for (int mm = 0; mm < 4; ++mm)                         \
        _Pragma("unroll") for (int n = 0; n < 4; ++n)                            \
            acc[(MB) + mm][n] = __builtin_amdgcn_mfma_i32_16x16x64_i8(           \
                a[mm], b[n], acc[(MB) + mm][n], 0, 0, 0);                        \
    } while (0)

// One K-tile = 4 phases (8/4/8/4 ds_reads, 16 MFMA each).
// Stage ring: P1->(t+1).A.ks1  P2->(t+2).B.ks0  P3->(t+2).A.ks0  P4->(t+2).B.ks1
#define TILE(T, CUR, S1, S2, S3, S4, VM)                                         \
    {                                                                            \
        _Pragma("unroll") for (int mm = 0; mm < 4; ++mm) a[mm] = rdA(CUR, 0, mm);\
        _Pragma("unroll") for (int n = 0; n < 4; ++n)    b[n]  = rdB(CUR, 0, n); \
        S1; bar(); PRIO1; QUAD(0); PRIO0; bar();                                 \
        _Pragma("unroll") for (int mm = 0; mm < 4; ++mm) a[mm] = rdA(CUR, 0, 4 + mm); \
        S2; bar(); PRIO1; QUAD(4); PRIO0; bar();                                 \
        _Pragma("unroll") for (int mm = 0; mm < 4; ++mm) a[mm] = rdA(CUR, 1, mm);\
        _Pragma("unroll") for (int n = 0; n < 4; ++n)    b[n]  = rdB(CUR, 1, n); \
        S3; bar(); PRIO1; QUAD(0); PRIO0; bar();                                 \
        _Pragma("unroll") for (int mm = 0; mm < 4; ++mm) a[mm] = rdA(CUR, 1, 4 + mm); \
        S4; bar(); PRIO1; QUAD(4); PRIO0; VM; bar();                             \
    }

__global__ __launch_bounds__(512, 2)
void gemm8(const char* __restrict__ A8, const char* __restrict__ B8,
           const int* __restrict__ bias,
           const int* __restrict__ qm_p, const int* __restrict__ ex_p,
           const int* __restrict__ zp_p, int* __restrict__ out) {
    // LDS: A [2 buf][2 ks][256 rows][64 B] at 0, B same at 65536 -> 128 KiB
    __shared__ __align__(16) char smem[131072];

    const int tid  = threadIdx.x;
    const int wid  = tid >> 6;
    const int lane = tid & 63;
    const int l15  = lane & 15;
    const int lks  = lane >> 4;
    const int wr   = wid >> 2;   // 0..1
    const int wc   = wid & 3;    // 0..3

    // XCD swizzle: 256 blocks, each XCD gets one bm stripe
    const int bid = blockIdx.x;
    const int swz = (bid & 7) * 32 + (bid >> 3);
    const int bm  = swz >> 5;    // 0..7
    const int bn  = swz & 31;    // 0..31
    const int arow0 = bm * 256;
    const int brow0 = bn * 256;

    // T2 swizzle: phys_slot = chunk ^ ((row>>1)&3); row bases 16-aligned =>
    // fragment-read selector depends only on (l15>>1)&3
    const int sw16 = (lks ^ ((l15 >> 1) & 3)) * 16;
    const int a_rd = (wr * 128 + l15) * 64 + sw16;
    const int b_rd = 65536 + (wc * 64 + l15) * 64 + sw16;

    // stage addressing: thread covers (row = tid>>2 [+128], chunk = st_c)
    const int st_c = (tid & 3) ^ ((tid >> 3) & 3);
    const char* agp = A8 + (size_t)(arow0 + (tid >> 2)) * Kdim + st_c * 16;
    const char* bgp = B8 + (size_t)(brow0 + (tid >> 2)) * Kdim + st_c * 16;

    auto stage = [&](int isb, int t, int ks) {
        const char* gp = (isb ? bgp : agp) + (size_t)t * BK + ks * 64;
        const int lb = (isb ? 65536 : 0) + (t & 1) * 32768 + ks * 16384 + tid * 16;
        gload_lds16(gp, &smem[lb]);
        gload_lds16(gp + (size_t)128 * Kdim, &smem[lb + 8192]);
    };
    auto rdA = [&](int buf, int ks, int m) {
        return *(const i32x4*)&smem[buf * 32768 + ks * 16384 + a_rd + m * 1024];
    };
    auto rdB = [&](int buf, int ks, int n) {
        return *(const i32x4*)&smem[buf * 32768 + ks * 16384 + b_rd + n * 1024];
    };

    i32x4 acc[8][4] = {};
    i32x4 a[4], b[4];

    // prologue: 7 units in steady-state order; vmcnt(6) => tile 0 landed
    stage(1, 0, 0); stage(0, 0, 0); stage(1, 0, 1); stage(0, 0, 1);
    stage(1, 1, 0); stage(0, 1, 0); stage(1, 1, 1);
    WAITVM(6);
    bar();

    int cur = 0;
    for (int t = 0; t < NT - 2; ++t) {   // t = 0..29, all stages valid
        TILE(t, cur,
             stage(0, t + 1, 1),
             stage(1, t + 2, 0),
             stage(0, t + 2, 0),
             stage(1, t + 2, 1),
             WAITVM(6));
        cur ^= 1;
    }
    // t = NT-2: only (NT-1).A.ks1 left to stage; drain fully
    TILE(NT - 2, cur,
         stage(0, NT - 1, 1),
         ((void)0), ((void)0), ((void)0),
         WAITVM(0));
    cur ^= 1;
    // t = NT-1: pure compute
    TILE(NT - 1, cur, ((void)0), ((void)0), ((void)0), ((void)0), ((void)0));

    // ---------------- epilogue: requantize ----------------
    const int qm = *qm_p;
    const int ex = *ex_p;
    const int zp = *zp_p;
    const int rm = (qm < 2147418112) ? ((qm + (1 << 15)) >> 16) : 32767;
    const int shifts = 15 - ex;
    const long long rnd = (shifts > 0) ? (1LL << (shifts - 1)) : 0;

    int bv[4];
#pragma unroll
    for (int n = 0; n < 4; ++n) bv[n] = bias[brow0 + wc * 64 + n * 16 + l15];

#pragma unroll
    for (int m = 0; m < 8; ++m) {
        const int row0 = arow0 + wr * 128 + m * 16 + lks * 4;
#pragma unroll
        for (int n = 0; n < 4; ++n) {
            const int col = brow0 + wc * 64 + n * 16 + l15;
#pragma unroll
            for (int j = 0; j < 4; ++j) {
                long long t = (long long)(acc[m][n][j] + bv[n]) * rm + rnd;
                t >>= shifts;
                t += zp;
                t = t < -128 ? -128 : (t > 127 ? 127 : t);
                out[(size_t)(row0 + j) * Ndim + col] = (int)t;
            }
        }
    }
}

extern "C" void kernel_launch(void* const* d_in, const int* in_sizes, int n_in,
                              void* d_out, int out_size, void* d_ws, size_t ws_size,
                              hipStream_t stream) {
    const int* x32  = (const int*)d_in[0];
    const int* w32  = (const int*)d_in[1];
    const int* bias = (const int*)d_in[2];
    const int* qm   = (const int*)d_in[3];
    const int* ex   = (const int*)d_in[4];
    const int* zp   = (const int*)d_in[5];
    int* out = (int*)d_out;

    char* xa = (char*)d_ws;
    char* wa = xa + (size_t)Bdim * Kdim;
    const int nx16 = Bdim * Kdim / 16;   // 524288
    const int nw16 = Ndim * Kdim / 16;   // 2097152
    pack_i32_to_i8<<<(nx16 + 255) / 256, 256, 0, stream>>>(x32, xa, nx16);
    pack_i32_to_i8<<<(nw16 + 255) / 256, 256, 0, stream>>>(w32, wa, nw16);

    const int grid = (Bdim / 256) * (Ndim / 256);   // 8 * 32 = 256
    gemm8<<<grid, 512, 0, stream>>>(xa, wa, bias, qm, ex, zp, out);
}

// Round 4
// 105.756 us; speedup vs baseline: 1.2166x; 1.0194x over previous
//
#include <hip/hip_runtime.h>

#define DEVI __device__ __forceinline__

typedef int i32x4 __attribute__((ext_vector_type(4)));

static constexpr int Bdim = 2048;
static constexpr int Kdim = 4096;
static constexpr int Ndim = 8192;
static constexpr int BK   = 128;         // int8 k-elements per tile (128 B/row)
static constexpr int NT   = Kdim / BK;   // 32 K-tiles

typedef __attribute__((address_space(1))) const unsigned int gas_t;
typedef __attribute__((address_space(3))) unsigned int las_t;
typedef __attribute__((address_space(3))) const char lds_cchar;

DEVI void gload_lds16(const void* g, void* l) {
    __builtin_amdgcn_global_load_lds((gas_t*)g, (las_t*)l, 16, 0, 0);
}

DEVI i32x4 dsread128(lds_cchar* p) {
    i32x4 r;
    asm volatile("ds_read_b128 %0, %1" : "=v"(r) : "v"(p));
    return r;
}

DEVI int pack4(i32x4 v) {
    return (v[0] & 255) | ((v[1] & 255) << 8) | ((v[2] & 255) << 16) | (v[3] << 24);
}

// ---------------- pack: int32 -> int8 ----------------
__global__ void pack_i32_to_i8(const int* __restrict__ in, char* __restrict__ out, int n16) {
    int i = blockIdx.x * blockDim.x + threadIdx.x;
    if (i >= n16) return;
    const i32x4* src = (const i32x4*)in + (size_t)i * 4;
    i32x4 r;
    r[0] = pack4(src[0]);
    r[1] = pack4(src[1]);
    r[2] = pack4(src[2]);
    r[3] = pack4(src[3]);
    ((i32x4*)out)[i] = r;
}

// ---------------- 256x256 8-phase i8 GEMM ----------------
#define CFENCE asm volatile("" ::: "memory")
DEVI void bar() { CFENCE; __builtin_amdgcn_s_barrier(); CFENCE; }
#define WAITVM(N) asm volatile("s_waitcnt vmcnt(" #N ")" ::: "memory")
#define WAITLGKM asm volatile("s_waitcnt lgkmcnt(0)" ::: "memory")
#define SCHB __builtin_amdgcn_sched_barrier(0)
#define PRIO1 __builtin_amdgcn_s_setprio(1)
#define PRIO0 __builtin_amdgcn_s_setprio(0)

// acc[MB..MB+3][0..3] += a[0..3] x b[0..3], compile-time MB (rule #20)
#define QUAD(MB)                                                                 \
    do {                                                                         \
        _Pragma("unroll") for (int mm = 0; mm < 4; ++mm)                         \
        _Pragma("unroll") for (int n = 0; n < 4; ++n)                            \
            acc[(MB) + mm][n] = __builtin_amdgcn_mfma_i32_16x16x64_i8(           \
                a[mm], b[n], acc[(MB) + mm][n], 0, 0, 0);                        \
    } while (0)

// One K-tile = 4 phases. Phase: reads ; stage ; bar ; lgkm(0) ; sched_barrier ;
// prio1 ; 16 MFMA ; prio0 ; [vmcnt] ; bar.
// Stage ring: P1->(t+1).A.ks1  P2->(t+2).B.ks0  P3->(t+2).A.ks0  P4->(t+2).B.ks1
#define TILE(CUR, S1, S2, S3, S4, VM)                                                 \
    {                                                                                 \
        { _Pragma("unroll") for (int mm = 0; mm < 4; ++mm) a[mm] = rdA(CUR, 0, mm);   \
          _Pragma("unroll") for (int n = 0; n < 4; ++n)    b[n]  = rdB(CUR, 0, n);    \
          S1; bar(); WAITLGKM; SCHB; PRIO1; QUAD(0); PRIO0; bar(); }                  \
        { _Pragma("unroll") for (int mm = 0; mm < 4; ++mm) a[mm] = rdA(CUR, 0, 4+mm); \
          S2; bar(); WAITLGKM; SCHB; PRIO1; QUAD(4); PRIO0; bar(); }                  \
        { _Pragma("unroll") for (int mm = 0; mm < 4; ++mm) a[mm] = rdA(CUR, 1, mm);   \
          _Pragma("unroll") for (int n = 0; n < 4; ++n)    b[n]  = rdB(CUR, 1, n);    \
          S3; bar(); WAITLGKM; SCHB; PRIO1; QUAD(0); PRIO0; bar(); }                  \
        { _Pragma("unroll") for (int mm = 0; mm < 4; ++mm) a[mm] = rdA(CUR, 1, 4+mm); \
          S4; bar(); WAITLGKM; SCHB; PRIO1; QUAD(4); PRIO0; VM; bar(); }              \
    }

__global__ __launch_bounds__(512, 2)
void gemm8(const char* __restrict__ A8, const char* __restrict__ B8,
           const int* __restrict__ bias,
           const int* __restrict__ qm_p, const int* __restrict__ ex_p,
           const int* __restrict__ zp_p, int* __restrict__ out) {
    // LDS: A [2 buf][2 ks][256 rows][64 B] at 0, B same at 65536 -> 128 KiB
    __shared__ __align__(16) char smem[131072];
    lds_cchar* sbase = (lds_cchar*)smem;

    const int tid  = threadIdx.x;
    const int wid  = tid >> 6;
    const int lane = tid & 63;
    const int l15  = lane & 15;
    const int lks  = lane >> 4;
    const int wr   = wid >> 2;   // 0..1
    const int wc   = wid & 3;    // 0..3

    // XCD swizzle: 256 blocks, each XCD gets one bm stripe
    const int bid = blockIdx.x;
    const int swz = (bid & 7) * 32 + (bid >> 3);
    const int bm  = swz >> 5;    // 0..7
    const int bn  = swz & 31;    // 0..31
    const int arow0 = bm * 256;
    const int brow0 = bn * 256;

    // T2 swizzle: phys_slot = chunk ^ ((row>>1)&3); row bases 16-aligned =>
    // fragment-read selector depends only on (l15>>1)&3
    const int sw16 = (lks ^ ((l15 >> 1) & 3)) * 16;
    const int a_rd = (wr * 128 + l15) * 64 + sw16;
    const int b_rd = 65536 + (wc * 64 + l15) * 64 + sw16;

    // stage addressing: thread covers (row = tid>>2 [+128], chunk = st_c)
    const int st_c = (tid & 3) ^ ((tid >> 3) & 3);
    const char* agp = A8 + (size_t)(arow0 + (tid >> 2)) * Kdim + st_c * 16;
    const char* bgp = B8 + (size_t)(brow0 + (tid >> 2)) * Kdim + st_c * 16;

    auto stage = [&](int isb, int t, int ks) {
        const char* gp = (isb ? bgp : agp) + (size_t)t * BK + ks * 64;
        const int lb = (isb ? 65536 : 0) + (t & 1) * 32768 + ks * 16384 + tid * 16;
        gload_lds16(gp, &smem[lb]);
        gload_lds16(gp + (size_t)128 * Kdim, &smem[lb + 8192]);
    };
    auto rdA = [&](int buf, int ks, int m) {
        return dsread128(sbase + (buf * 32768 + ks * 16384 + a_rd + m * 1024));
    };
    auto rdB = [&](int buf, int ks, int n) {
        return dsread128(sbase + (buf * 32768 + ks * 16384 + b_rd + n * 1024));
    };

    i32x4 acc[8][4] = {};
    i32x4 a[4], b[4];

    // prologue: 7 units in steady-state order; vmcnt(6) => tile 0 landed
    stage(1, 0, 0); stage(0, 0, 0); stage(1, 0, 1); stage(0, 0, 1);
    stage(1, 1, 0); stage(0, 1, 0); stage(1, 1, 1);
    WAITVM(6);
    bar();

    int cur = 0;
    for (int t = 0; t < NT - 2; ++t) {   // t = 0..29, all stages valid
        TILE(cur,
             stage(0, t + 1, 1),
             stage(1, t + 2, 0),
             stage(0, t + 2, 0),
             stage(1, t + 2, 1),
             WAITVM(6));
        cur ^= 1;
    }
    // t = NT-2: only (NT-1).A.ks1 left to stage; drain fully
    TILE(cur,
         stage(0, NT - 1, 1),
         ((void)0), ((void)0), ((void)0),
         WAITVM(0));
    cur ^= 1;
    // t = NT-1: pure compute
    TILE(cur, ((void)0), ((void)0), ((void)0), ((void)0), ((void)0));

    // ---------------- epilogue: requantize ----------------
    const int qm = *qm_p;
    const int ex = *ex_p;
    const int zp = *zp_p;
    const int rm = (qm < 2147418112) ? ((qm + (1 << 15)) >> 16) : 32767;
    const int shifts = 15 - ex;
    const long long rnd = (shifts > 0) ? (1LL << (shifts - 1)) : 0;

    int bv[4];
#pragma unroll
    for (int n = 0; n < 4; ++n) bv[n] = bias[brow0 + wc * 64 + n * 16 + l15];

#pragma unroll
    for (int m = 0; m < 8; ++m) {
        const int row0 = arow0 + wr * 128 + m * 16 + lks * 4;
#pragma unroll
        for (int n = 0; n < 4; ++n) {
            const int col = brow0 + wc * 64 + n * 16 + l15;
#pragma unroll
            for (int j = 0; j < 4; ++j) {
                long long t = (long long)(acc[m][n][j] + bv[n]) * rm + rnd;
                t >>= shifts;
                t += zp;
                t = t < -128 ? -128 : (t > 127 ? 127 : t);
                out[(size_t)(row0 + j) * Ndim + col] = (int)t;
            }
        }
    }
}

extern "C" void kernel_launch(void* const* d_in, const int* in_sizes, int n_in,
                              void* d_out, int out_size, void* d_ws, size_t ws_size,
                              hipStream_t stream) {
    const int* x32  = (const int*)d_in[0];
    const int* w32  = (const int*)d_in[1];
    const int* bias = (const int*)d_in[2];
    const int* qm   = (const int*)d_in[3];
    const int* ex   = (const int*)d_in[4];
    const int* zp   = (const int*)d_in[5];
    int* out = (int*)d_out;

    char* xa = (char*)d_ws;
    char* wa = xa + (size_t)Bdim * Kdim;
    const int nx16 = Bdim * Kdim / 16;   // 524288
    const int nw16 = Ndim * Kdim / 16;   // 2097152
    pack_i32_to_i8<<<(nx16 + 255) / 256, 256, 0, stream>>>(x32, xa, nx16);
    pack_i32_to_i8<<<(nw16 + 255) / 256, 256, 0, stream>>>(w32, wa, nw16);

    const int grid = (Bdim / 256) * (Ndim / 256);   // 8 * 32 = 256
    gemm8<<<grid, 512, 0, stream>>>(xa, wa, bias, qm, ex, zp, out);
}